// Round 5
// baseline (46.590 us; speedup 1.0000x reference)
//
#include <hip/hip_runtime.h>

// Cubic Hermite spline fwd (nsf cubic_spline, inverse=False), elementwise.
// Round 5: per-element float4 param loads via a 16B-aligned 36-float window
// (fs = 34i & ~3, off in {0,2}); 9 strided wave-instrs per element instead of
// 17 -> halves L1 line-lookup traffic. Component selection by compile-time
// index + one cndmask on `off` (no runtime-indexed arrays, no divergence).
// Math: round-4 lean fused scan. VGPR target < 128 (launch_bounds(256,4)).

namespace {

constexpr int K = 16;
constexpr float MBW = 0.001f;     // MIN_BIN_WIDTH
constexpr float MBH = 0.001f;     // MIN_BIN_HEIGHT

__device__ __forceinline__ float frcp(float x) { return __builtin_amdgcn_rcpf(x); }
__device__ __forceinline__ float fsgn(float v) { return (v > 0.f) ? 1.f : ((v < 0.f) ? -1.f : 0.f); }
__device__ __forceinline__ float fsigmoid(float x) { return frcp(1.f + __expf(-x)); }

// component m (compile-time constant) of the 36-float window
__device__ __forceinline__ float f4c(const float4 (&g)[9], int m) {
    const float4 v = g[m >> 2];
    switch (m & 3) { case 0: return v.x; case 1: return v.y; case 2: return v.z; default: return v.w; }
}

__global__ __launch_bounds__(256, 4) void cubic_spline_fwd_kernel(
    const float* __restrict__ xlo,
    const float* __restrict__ xup,
    const float* __restrict__ params,
    float* __restrict__ out,
    int N)
{
    const int i = blockIdx.x * 256 + threadIdx.x;
    if (i >= N) return;

    // ---- load 36-float aligned window covering this element's 34 params ----
    const size_t base = (size_t)i * 34;
    const size_t fs = base & ~(size_t)3;     // 16B-aligned float index
    const bool sh2 = (base & 3) != 0;        // off == 2 ?

    const float4* p4 = reinterpret_cast<const float4*>(params + fs);
    float4 g[9];
    #pragma unroll
    for (int k = 0; k < 8; ++k) g[k] = p4[k];
    if (fs + 36 <= (size_t)N * 34) {
        g[8] = p4[8];
    } else {                                  // last element, off==0: avoid 8B overrun
        const float2 t2 = *reinterpret_cast<const float2*>(params + fs + 32);
        g[8] = make_float4(t2.x, t2.y, 0.f, 0.f);
    }

    const float x0 = xlo[i];
    const float x1 = xup[i];

    // param m of this element = window[m + (sh2 ? 2 : 0)], m compile-time
    #define PF(m) (sh2 ? f4c(g, (m) + 2) : f4c(g, (m)))

    // ---- softmax over widths (params 0..15) ----
    float mw = PF(0);
    #pragma unroll
    for (int j = 1; j < K; ++j) mw = fmaxf(mw, PF(j));
    float w[K];
    float sw = 0.f;
    #pragma unroll
    for (int j = 0; j < K; ++j) { w[j] = __expf(PF(j) - mw); sw += w[j]; }
    const float cw_scale = (1.0f - MBW * K) * frcp(sw);
    #pragma unroll
    for (int j = 0; j < K; ++j) w[j] = MBW + w[j] * cw_scale;

    // ---- softmax over heights (params 16..31) -> slopes s = h/w ----
    float mh = PF(16);
    #pragma unroll
    for (int j = 1; j < K; ++j) mh = fmaxf(mh, PF(16 + j));
    float s[K];
    float sh = 0.f;
    #pragma unroll
    for (int j = 0; j < K; ++j) { s[j] = __expf(PF(16 + j) - mh); sh += s[j]; }
    const float ch_scale = (1.0f - MBH * K) * frcp(sh);
    #pragma unroll
    for (int j = 0; j < K; ++j) {
        const float hj = MBH + s[j] * ch_scale;
        s[j] = hj * frcp(w[j]);
    }

    const float udl = PF(32);
    const float udr = PF(33);
    #undef PF

    // ---- fused scan: stream Hermite knot derivatives, select bin coeffs ----
    // knots cw(j) = sum_{m<j} w[m]; x in [0,1): last bin with knot <= x wins.
    float dv_cur = fsigmoid(udl) * 3.f * s[0];
    float cw = 0.f, ch = 0.f;
    float a0 = 0.f, b0 = 0.f, c0 = 0.f, d0 = 0.f, l0 = 0.f;
    float a1 = 0.f, b1 = 0.f, c1 = 0.f, d1 = 0.f, l1 = 0.f;
    #pragma unroll
    for (int j = 0; j < K; ++j) {
        float dv_next;
        if (j < K - 1) {
            const float s0 = s[j], s1 = s[j + 1];
            const float w0 = w[j], w1 = w[j + 1];
            const float min1 = fminf(fabsf(s0), fabsf(s1));
            const float min2 = 0.5f * (w1 * s0 + w0 * s1) * frcp(w0 + w1);
            dv_next = fminf(min1, min2) * (fsgn(s0) + fsgn(s1));
        } else {
            dv_next = fsigmoid(udr) * 3.f * s[K - 1];
        }
        const float rwj = frcp(w[j]);
        const float aj = (dv_cur + dv_next - 2.f * s[j]) * (rwj * rwj);
        const float bj = (3.f * s[j] - 2.f * dv_cur - dv_next) * rwj;
        const float cj = dv_cur;
        const float dj = ch;
        const bool t0 = (j == 0) | (x0 >= cw);
        const bool t1 = (j == 0) | (x1 >= cw);
        a0 = t0 ? aj : a0; b0 = t0 ? bj : b0; c0 = t0 ? cj : c0;
        d0 = t0 ? dj : d0; l0 = t0 ? cw : l0;
        a1 = t1 ? aj : a1; b1 = t1 ? bj : b1; c1 = t1 ? cj : c1;
        d1 = t1 ? dj : d1; l1 = t1 ? cw : l1;
        cw += w[j];
        ch += s[j] * w[j];
        dv_cur = dv_next;
    }

    float t = x0 - l0;
    const float z0 = ((a0 * t + b0) * t + c0) * t + d0;
    t = x1 - l1;
    const float z1 = ((a1 * t + b1) * t + c1) * t + d1;

    out[i]     = fminf(fmaxf(z0, 0.f), 1.f);
    out[N + i] = fminf(fmaxf(z1, 0.f), 1.f);
}

}  // namespace

extern "C" void kernel_launch(void* const* d_in, const int* in_sizes, int n_in,
                              void* d_out, int out_size, void* d_ws, size_t ws_size,
                              hipStream_t stream) {
    const float* xlo    = (const float*)d_in[0];
    const float* xup    = (const float*)d_in[1];
    const float* params = (const float*)d_in[2];
    float* out = (float*)d_out;
    const int N = in_sizes[0];

    const int block = 256;
    const int grid = (N + block - 1) / block;
    cubic_spline_fwd_kernel<<<grid, block, 0, stream>>>(xlo, xup, params, out, N);
}

// Round 6
// 42.412 us; speedup vs baseline: 1.0985x; 1.0985x over previous
//
#include <hip/hip_runtime.h>

// Cubic Hermite spline fwd (nsf cubic_spline, inverse=False), elementwise.
// Round 6: per-element float4 param loads from the element's OWN base
// (8 x dwordx4 + 1 x dwordx2 = 10 wave-instrs vs round 4's 17), zero
// select overhead, same register footprint/math as round 4 (42.25 us).
// Odd elements' slabs are 8B-aligned: gfx950 supports unaligned global
// dwordx4 (single transaction unless 64B-line-crossing, ~19% of loads).
// aligned(4) vector typedef makes the 8B-aligned load well-defined.
// All K=16 loops fully unrolled - static register indexing only.

namespace {

constexpr int K = 16;
constexpr float MBW = 0.001f;     // MIN_BIN_WIDTH
constexpr float MBH = 0.001f;     // MIN_BIN_HEIGHT

typedef float f32x4 __attribute__((ext_vector_type(4), aligned(4)));
typedef float f32x2 __attribute__((ext_vector_type(2), aligned(4)));

__device__ __forceinline__ float frcp(float x) { return __builtin_amdgcn_rcpf(x); }
__device__ __forceinline__ float fsgn(float v) { return (v > 0.f) ? 1.f : ((v < 0.f) ? -1.f : 0.f); }
__device__ __forceinline__ float fsigmoid(float x) { return frcp(1.f + __expf(-x)); }

__global__ __launch_bounds__(256, 4) void cubic_spline_fwd_kernel(
    const float* __restrict__ xlo,
    const float* __restrict__ xup,
    const float* __restrict__ params,
    float* __restrict__ out,
    int N)
{
    const int i = blockIdx.x * 256 + threadIdx.x;
    if (i >= N) return;

    // ---- load this element's 34 params: 8 x float4 + 1 x float2 ----
    const float* p = params + (size_t)i * 34;
    f32x4 q[8];
    #pragma unroll
    for (int k = 0; k < 8; ++k)
        q[k] = *reinterpret_cast<const f32x4*>(p + 4 * k);
    const f32x2 ud2 = *reinterpret_cast<const f32x2*>(p + 32);

    const float x0 = xlo[i];
    const float x1 = xup[i];

    // param m (compile-time constant), m in [0,32)
    #define PF(m) (q[(m) >> 2][(m) & 3])

    // ---- softmax over widths (params 0..15) ----
    float mw = PF(0);
    #pragma unroll
    for (int j = 1; j < K; ++j) mw = fmaxf(mw, PF(j));
    float w[K];
    float sw = 0.f;
    #pragma unroll
    for (int j = 0; j < K; ++j) { w[j] = __expf(PF(j) - mw); sw += w[j]; }
    const float cw_scale = (1.0f - MBW * K) * frcp(sw);
    #pragma unroll
    for (int j = 0; j < K; ++j) w[j] = MBW + w[j] * cw_scale;

    // ---- softmax over heights (params 16..31) -> slopes s = h/w ----
    float mh = PF(16);
    #pragma unroll
    for (int j = 1; j < K; ++j) mh = fmaxf(mh, PF(16 + j));
    float s[K];
    float sh = 0.f;
    #pragma unroll
    for (int j = 0; j < K; ++j) { s[j] = __expf(PF(16 + j) - mh); sh += s[j]; }
    const float ch_scale = (1.0f - MBH * K) * frcp(sh);
    #pragma unroll
    for (int j = 0; j < K; ++j) {
        const float hj = MBH + s[j] * ch_scale;
        s[j] = hj * frcp(w[j]);
    }
    #undef PF

    const float udl = ud2[0], udr = ud2[1];

    // ---- fused scan: stream Hermite knot derivatives, select bin coeffs ----
    // knots cw(j) = sum_{m<j} w[m]; x in [0,1): last bin with knot <= x wins.
    float dv_cur = fsigmoid(udl) * 3.f * s[0];
    float cw = 0.f, ch = 0.f;
    float a0 = 0.f, b0 = 0.f, c0 = 0.f, d0 = 0.f, l0 = 0.f;
    float a1 = 0.f, b1 = 0.f, c1 = 0.f, d1 = 0.f, l1 = 0.f;
    #pragma unroll
    for (int j = 0; j < K; ++j) {
        float dv_next;
        if (j < K - 1) {
            const float s0 = s[j], s1 = s[j + 1];
            const float w0 = w[j], w1 = w[j + 1];
            const float min1 = fminf(fabsf(s0), fabsf(s1));
            const float min2 = 0.5f * (w1 * s0 + w0 * s1) * frcp(w0 + w1);
            dv_next = fminf(min1, min2) * (fsgn(s0) + fsgn(s1));
        } else {
            dv_next = fsigmoid(udr) * 3.f * s[K - 1];
        }
        const float rwj = frcp(w[j]);
        const float aj = (dv_cur + dv_next - 2.f * s[j]) * (rwj * rwj);
        const float bj = (3.f * s[j] - 2.f * dv_cur - dv_next) * rwj;
        const float cj = dv_cur;
        const float dj = ch;
        const bool t0 = (j == 0) | (x0 >= cw);
        const bool t1 = (j == 0) | (x1 >= cw);
        a0 = t0 ? aj : a0; b0 = t0 ? bj : b0; c0 = t0 ? cj : c0;
        d0 = t0 ? dj : d0; l0 = t0 ? cw : l0;
        a1 = t1 ? aj : a1; b1 = t1 ? bj : b1; c1 = t1 ? cj : c1;
        d1 = t1 ? dj : d1; l1 = t1 ? cw : l1;
        cw += w[j];
        ch += s[j] * w[j];
        dv_cur = dv_next;
    }

    float t = x0 - l0;
    const float z0 = ((a0 * t + b0) * t + c0) * t + d0;
    t = x1 - l1;
    const float z1 = ((a1 * t + b1) * t + c1) * t + d1;

    out[i]     = fminf(fmaxf(z0, 0.f), 1.f);
    out[N + i] = fminf(fmaxf(z1, 0.f), 1.f);
}

}  // namespace

extern "C" void kernel_launch(void* const* d_in, const int* in_sizes, int n_in,
                              void* d_out, int out_size, void* d_ws, size_t ws_size,
                              hipStream_t stream) {
    const float* xlo    = (const float*)d_in[0];
    const float* xup    = (const float*)d_in[1];
    const float* params = (const float*)d_in[2];
    float* out = (float*)d_out;
    const int N = in_sizes[0];

    const int block = 256;
    const int grid = (N + block - 1) / block;
    cubic_spline_fwd_kernel<<<grid, block, 0, stream>>>(xlo, xup, params, out, N);
}